// Round 3
// baseline (226.986 us; speedup 1.0000x reference)
//
#include <hip/hip_runtime.h>
#include <math.h>

// Grayscale morphological dilation, 7x7 additive SE, zero 'same' padding:
//   out[p, i, j] = max_{a,b in 0..6} ( xz(p, i+a-3, j+b-3) + w[a,b] )
//
// Thread tile: 8 wide x 8 tall. Block 256 = 32 thread-cols x 8 thread-rows
// -> 256x64 tile; grid (2, 8, 64) covers 512x512x64 exactly (no tail).
// All global loads are UNCONDITIONAL: out-of-bounds chunks have their
// address cndmask'd to a 16B device-side zero page (exact zero padding,
// no divergent branches -> scheduler pipelines loads freely).
// Explicit even/odd register double-buffer: load input row k+1 while
// computing row k. Static indexing everywhere -> registers only.
// Weights forced to SGPRs via readfirstlane.

#define HH 512
#define WW 512

__device__ __align__(16) const float ZPAGE[4] = {0.f, 0.f, 0.f, 0.f};

#define LOADROW(RV, K)                                                       \
  {                                                                          \
    const int r_ = row0 - 3 + (K);                                           \
    const bool rok_ = ((unsigned)r_ < (unsigned)HH);                         \
    const float* rp_ = xp + (ptrdiff_t)r_ * WW + (col0 - 4);                 \
    const float* p0_ = (rok_ && okL) ? rp_ : zp;                             \
    const float* p1_ = rok_ ? rp_ + 4 : zp;                                  \
    const float* p2_ = rok_ ? rp_ + 8 : zp;                                  \
    const float* p3_ = (rok_ && okR) ? rp_ + 12 : zp;                        \
    float4 v0_ = *reinterpret_cast<const float4*>(p0_);                      \
    float4 v1_ = *reinterpret_cast<const float4*>(p1_);                      \
    float4 v2_ = *reinterpret_cast<const float4*>(p2_);                      \
    float4 v3_ = *reinterpret_cast<const float4*>(p3_);                      \
    RV[0] = v0_.x;  RV[1] = v0_.y;  RV[2] = v0_.z;  RV[3] = v0_.w;           \
    RV[4] = v1_.x;  RV[5] = v1_.y;  RV[6] = v1_.z;  RV[7] = v1_.w;           \
    RV[8] = v2_.x;  RV[9] = v2_.y;  RV[10] = v2_.z; RV[11] = v2_.w;          \
    RV[12] = v3_.x; RV[13] = v3_.y; RV[14] = v3_.z; RV[15] = v3_.w;          \
  }

#define COMPROW(RV, K)                                                       \
  {                                                                          \
    _Pragma("unroll") for (int t = 0; t < 8; ++t) {                          \
      if (t >= (K) - 6 && t <= (K)) { /* SE row a = K-t in 0..6 */           \
        const int a_ = (K) - t;                                              \
        _Pragma("unroll") for (int j = 0; j < 8; ++j) {                      \
          /* tap b: input col col0+j+b-3 -> RV[j+b+1] */                     \
          float m_ = acc[t][j];                                              \
          float c0_ = RV[j + 1] + wv[a_ * 7 + 0];                            \
          float c1_ = RV[j + 2] + wv[a_ * 7 + 1];                            \
          m_ = fmaxf(m_, fmaxf(c0_, c1_)); /* v_max3_f32 */                  \
          float c2_ = RV[j + 3] + wv[a_ * 7 + 2];                            \
          float c3_ = RV[j + 4] + wv[a_ * 7 + 3];                            \
          m_ = fmaxf(m_, fmaxf(c2_, c3_));                                   \
          float c4_ = RV[j + 5] + wv[a_ * 7 + 4];                            \
          float c5_ = RV[j + 6] + wv[a_ * 7 + 5];                            \
          m_ = fmaxf(m_, fmaxf(c4_, c5_));                                   \
          m_ = fmaxf(m_, RV[j + 7] + wv[a_ * 7 + 6]);                        \
          acc[t][j] = m_;                                                    \
        }                                                                    \
      }                                                                      \
    }                                                                        \
  }

__global__ __launch_bounds__(256, 4) void dilate7(const float* __restrict__ x,
                                                  const float* __restrict__ wg,
                                                  float* __restrict__ out) {
  const int tid = threadIdx.x;
  const int lc = tid & 31;                        // 32 thread-cols
  const int tr = tid >> 5;                        // 8 thread-rows
  const int col0 = blockIdx.x * 256 + lc * 8;     // output col base (mult of 8)
  const int row0 = blockIdx.y * 64 + tr * 8;      // output row base

  const size_t plane_off = (size_t)blockIdx.z * (size_t)(HH * WW);
  const float* xp = x + plane_off;
  float* op = out + plane_off;

  // Weights -> SGPRs (uniform across wave).
  float wv[49];
#pragma unroll
  for (int i = 0; i < 49; ++i)
    wv[i] = __int_as_float(__builtin_amdgcn_readfirstlane(__float_as_int(wg[i])));

  const float* zp = &ZPAGE[0];
  const bool okL = (col0 >= 4);        // left halo chunk fully in-bounds?
  const bool okR = (col0 + 12 <= WW);  // right halo chunk fully in-bounds?

  float acc[8][8];
#pragma unroll
  for (int t = 0; t < 8; ++t)
#pragma unroll
    for (int j = 0; j < 8; ++j) acc[t][j] = -INFINITY;

  float rvA[16], rvB[16];
  LOADROW(rvA, 0);
#pragma unroll
  for (int k = 0; k < 14; ++k) {
    if ((k & 1) == 0) {
      if (k < 13) LOADROW(rvB, k + 1);   // prefetch next row
      COMPROW(rvA, k);
    } else {
      if (k < 13) LOADROW(rvA, k + 1);
      COMPROW(rvB, k);
    }
  }

  // Stores: grid covers 512x512 exactly -> no guards.
#pragma unroll
  for (int t = 0; t < 8; ++t) {
    float* orow = op + (size_t)(row0 + t) * WW + col0;
    *reinterpret_cast<float4*>(orow) =
        make_float4(acc[t][0], acc[t][1], acc[t][2], acc[t][3]);
    *reinterpret_cast<float4*>(orow + 4) =
        make_float4(acc[t][4], acc[t][5], acc[t][6], acc[t][7]);
  }
}

extern "C" void kernel_launch(void* const* d_in, const int* in_sizes, int n_in,
                              void* d_out, int out_size, void* d_ws, size_t ws_size,
                              hipStream_t stream) {
  const float* x = (const float*)d_in[0];
  const float* w = (const float*)d_in[1];
  float* out = (float*)d_out;
  const int planes = in_sizes[0] / (HH * WW);   // 8*8 = 64
  dim3 grid(2, 8, planes);                      // 256x64 tile -> exact cover
  dilate7<<<grid, dim3(256, 1, 1), 0, stream>>>(x, w, out);
}

// Round 4
// 60.803 us; speedup vs baseline: 3.7332x; 3.7332x over previous
//
#include <hip/hip_runtime.h>
#include <math.h>

// Grayscale morphological dilation, 7x7 additive SE, zero 'same' padding:
//   out[p, i, j] = max_{a,b in 0..6} ( xz(p, i+a-3, j+b-3) + w[a,b] )
//
// Thread tile: 8 wide x 8 tall. Block 256 = 32 thread-cols x 8 thread-rows
// -> 256x64 tile; grid (2, 8, 64) covers 512x512x64 exactly (no tail).
// Branchless loads: OOB chunk addresses cndmask'd onto a 16B zero page
// (exact zero padding). Software pipeline written as an EXPLICIT sequence
// with literal row indices K -- no runtime-indexed arrays anywhere, so
// rvA/rvB/acc/wv all live in registers (R3's runtime-k loop failed to
// unroll and spilled everything to scratch: 462MB writes, 227us).
// Weights forced to SGPRs via readfirstlane.

#define HH 512
#define WW 512

__device__ __align__(16) const float ZPAGE[4] = {0.f, 0.f, 0.f, 0.f};

#define LOADROW(RV, K)                                                       \
  {                                                                          \
    const int r_ = row0 - 3 + (K);                                           \
    const bool rok_ = ((unsigned)r_ < (unsigned)HH);                         \
    const float* rp_ = xp + (ptrdiff_t)r_ * WW + (col0 - 4);                 \
    const float* p0_ = (rok_ && okL) ? rp_ : zp;                             \
    const float* p1_ = rok_ ? rp_ + 4 : zp;                                  \
    const float* p2_ = rok_ ? rp_ + 8 : zp;                                  \
    const float* p3_ = (rok_ && okR) ? rp_ + 12 : zp;                        \
    float4 v0_ = *reinterpret_cast<const float4*>(p0_);                      \
    float4 v1_ = *reinterpret_cast<const float4*>(p1_);                      \
    float4 v2_ = *reinterpret_cast<const float4*>(p2_);                      \
    float4 v3_ = *reinterpret_cast<const float4*>(p3_);                      \
    RV[0] = v0_.x;  RV[1] = v0_.y;  RV[2] = v0_.z;  RV[3] = v0_.w;           \
    RV[4] = v1_.x;  RV[5] = v1_.y;  RV[6] = v1_.z;  RV[7] = v1_.w;           \
    RV[8] = v2_.x;  RV[9] = v2_.y;  RV[10] = v2_.z; RV[11] = v2_.w;          \
    RV[12] = v3_.x; RV[13] = v3_.y; RV[14] = v3_.z; RV[15] = v3_.w;          \
  }

// K is ALWAYS a literal constant at expansion site; with the unrolled t-loop
// every condition and index below folds at compile time.
#define COMPROW(RV, K)                                                       \
  {                                                                          \
    _Pragma("unroll") for (int t = 0; t < 8; ++t) {                          \
      if (t <= (K) && t + 6 >= (K)) { /* SE row a = K-t in 0..6 */           \
        const int a_ = (K) - t;                                              \
        _Pragma("unroll") for (int j = 0; j < 8; ++j) {                      \
          /* tap b: input col col0+j+b-3 -> RV[j+b+1] */                     \
          const float c0_ = RV[j + 1] + wv[a_ * 7 + 0];                      \
          const float c1_ = RV[j + 2] + wv[a_ * 7 + 1];                      \
          float m_ = ((K) == t) ? fmaxf(c0_, c1_)       /* first touch */    \
                                : fmaxf(acc[t][j], fmaxf(c0_, c1_));         \
          const float c2_ = RV[j + 3] + wv[a_ * 7 + 2];                      \
          const float c3_ = RV[j + 4] + wv[a_ * 7 + 3];                      \
          m_ = fmaxf(m_, fmaxf(c2_, c3_));              /* v_max3_f32 */     \
          const float c4_ = RV[j + 5] + wv[a_ * 7 + 4];                      \
          const float c5_ = RV[j + 6] + wv[a_ * 7 + 5];                      \
          m_ = fmaxf(m_, fmaxf(c4_, c5_));                                   \
          m_ = fmaxf(m_, RV[j + 7] + wv[a_ * 7 + 6]);                        \
          acc[t][j] = m_;                                                    \
        }                                                                    \
      }                                                                      \
    }                                                                        \
  }

__global__ __launch_bounds__(256) void dilate7(const float* __restrict__ x,
                                               const float* __restrict__ wg,
                                               float* __restrict__ out) {
  const int tid = threadIdx.x;
  const int lc = tid & 31;                        // 32 thread-cols
  const int tr = tid >> 5;                        // 8 thread-rows
  const int col0 = blockIdx.x * 256 + lc * 8;     // output col base (mult of 8)
  const int row0 = blockIdx.y * 64 + tr * 8;      // output row base

  const size_t plane_off = (size_t)blockIdx.z * (size_t)(HH * WW);
  const float* xp = x + plane_off;
  float* op = out + plane_off;

  // Weights -> SGPRs (uniform across wave).
  float wv[49];
#pragma unroll
  for (int i = 0; i < 49; ++i)
    wv[i] = __int_as_float(__builtin_amdgcn_readfirstlane(__float_as_int(wg[i])));

  const float* zp = &ZPAGE[0];
  const bool okL = (col0 >= 4);        // left halo chunk fully in-bounds?
  const bool okR = (col0 + 12 <= WW);  // right halo chunk fully in-bounds?

  float acc[8][8];                     // no init needed: first write at K==t
  float rvA[16], rvB[16];

  // Explicit 1-row-ahead software pipeline, all K literal:
  LOADROW(rvA, 0);
  LOADROW(rvB, 1);   COMPROW(rvA, 0);
  LOADROW(rvA, 2);   COMPROW(rvB, 1);
  LOADROW(rvB, 3);   COMPROW(rvA, 2);
  LOADROW(rvA, 4);   COMPROW(rvB, 3);
  LOADROW(rvB, 5);   COMPROW(rvA, 4);
  LOADROW(rvA, 6);   COMPROW(rvB, 5);
  LOADROW(rvB, 7);   COMPROW(rvA, 6);
  LOADROW(rvA, 8);   COMPROW(rvB, 7);
  LOADROW(rvB, 9);   COMPROW(rvA, 8);
  LOADROW(rvA, 10);  COMPROW(rvB, 9);
  LOADROW(rvB, 11);  COMPROW(rvA, 10);
  LOADROW(rvA, 12);  COMPROW(rvB, 11);
  LOADROW(rvB, 13);  COMPROW(rvA, 12);
  COMPROW(rvB, 13);

  // Stores: grid covers 512x512 exactly -> no guards.
#pragma unroll
  for (int t = 0; t < 8; ++t) {
    float* orow = op + (size_t)(row0 + t) * WW + col0;
    *reinterpret_cast<float4*>(orow) =
        make_float4(acc[t][0], acc[t][1], acc[t][2], acc[t][3]);
    *reinterpret_cast<float4*>(orow + 4) =
        make_float4(acc[t][4], acc[t][5], acc[t][6], acc[t][7]);
  }
}

extern "C" void kernel_launch(void* const* d_in, const int* in_sizes, int n_in,
                              void* d_out, int out_size, void* d_ws, size_t ws_size,
                              hipStream_t stream) {
  const float* x = (const float*)d_in[0];
  const float* w = (const float*)d_in[1];
  float* out = (float*)d_out;
  const int planes = in_sizes[0] / (HH * WW);   // 8*8 = 64
  dim3 grid(2, 8, planes);                      // 256x64 tile -> exact cover
  dilate7<<<grid, dim3(256, 1, 1), 0, stream>>>(x, w, out);
}

// Round 6
// 53.309 us; speedup vs baseline: 4.2580x; 1.1406x over previous
//
#include <hip/hip_runtime.h>

// Grayscale morphological dilation, 7x7 additive SE, zero 'same' padding:
//   out[p, i, j] = max_{a,b in 0..6} ( xz(p, i+a-3, j+b-3) + w[a,b] )
//
// Block 256 = 64 thread-cols x 4 waves; thread tile 8x8
// -> block tile 512 cols x 32 rows; grid (16, 64) covers exactly.
// row0 is WAVE-UNIFORM (tid>>6) and forced scalar via readfirstlane:
// row-OOB handling is an SGPR cselect of the row base onto a zero row
// (no vector work before load issue; loads are saddr-form). Only lane 0
// (left chunk) / lane 63 (right chunk) need per-lane pointer cndmask.
// 2-deep software pipeline with 3 rotating literal-indexed buffers; output
// row t stored right after its last touch (K = t+6). No runtime-indexed
// arrays anywhere (R3 lesson: runtime k -> scratch, 4x slowdown).
// R5 bug fixed: 4th halo chunk is rb_+col0+8 (cols col0+8..11), NOT +12;
// okR is col0+12 <= WW.

#define HH 512
#define WW 512

__device__ __align__(16) const float ZROW[528] = {};  // all zeros

#define LOADROW(RV, K)                                                       \
  {                                                                          \
    const int r_ = row0 - 3 + (K);              /* scalar */                 \
    const float* rb_ = ((unsigned)r_ < (unsigned)HH)                         \
                           ? (xp + (ptrdiff_t)r_ * WW)                       \
                           : zrb;               /* s_cselect_b64 */          \
    const float* p0_ = okL ? rb_ + col0 - 4 : &ZROW[0];                      \
    const float* p3_ = okR ? rb_ + col0 + 8 : &ZROW[0];                      \
    float4 v0_ = *reinterpret_cast<const float4*>(p0_);                      \
    float4 v1_ = *reinterpret_cast<const float4*>(rb_ + col0);               \
    float4 v2_ = *reinterpret_cast<const float4*>(rb_ + col0 + 4);           \
    float4 v3_ = *reinterpret_cast<const float4*>(p3_);                      \
    RV[0] = v0_.x;  RV[1] = v0_.y;  RV[2] = v0_.z;  RV[3] = v0_.w;           \
    RV[4] = v1_.x;  RV[5] = v1_.y;  RV[6] = v1_.z;  RV[7] = v1_.w;           \
    RV[8] = v2_.x;  RV[9] = v2_.y;  RV[10] = v2_.z; RV[11] = v2_.w;          \
    RV[12] = v3_.x; RV[13] = v3_.y; RV[14] = v3_.z; RV[15] = v3_.w;          \
  }

// K is a literal at every expansion site; all indices fold at compile time.
#define COMPROW(RV, K)                                                       \
  {                                                                          \
    _Pragma("unroll") for (int t = 0; t < 8; ++t) {                          \
      if (t <= (K) && t + 6 >= (K)) { /* SE row a = K-t in 0..6 */           \
        const int a_ = (K) - t;                                              \
        _Pragma("unroll") for (int j = 0; j < 8; ++j) {                      \
          /* tap b: input col col0+j+b-3 -> RV[j+b+1] */                     \
          const float c0_ = RV[j + 1] + wv[a_ * 7 + 0];                      \
          const float c1_ = RV[j + 2] + wv[a_ * 7 + 1];                      \
          float m_ = ((K) == t) ? fmaxf(c0_, c1_)        /* first touch */   \
                                : fmaxf(acc[t][j], fmaxf(c0_, c1_));         \
          const float c2_ = RV[j + 3] + wv[a_ * 7 + 2];                      \
          const float c3_ = RV[j + 4] + wv[a_ * 7 + 3];                      \
          m_ = fmaxf(m_, fmaxf(c2_, c3_));               /* v_max3_f32 */    \
          const float c4_ = RV[j + 5] + wv[a_ * 7 + 4];                      \
          const float c5_ = RV[j + 6] + wv[a_ * 7 + 5];                      \
          m_ = fmaxf(m_, fmaxf(c4_, c5_));                                   \
          m_ = fmaxf(m_, RV[j + 7] + wv[a_ * 7 + 6]);                        \
          acc[t][j] = m_;                                                    \
        }                                                                    \
      }                                                                      \
    }                                                                        \
  }

#define STOREROW(T)                                                          \
  {                                                                          \
    float* orow_ = op + (ptrdiff_t)(row0 + (T)) * WW + col0;                 \
    *reinterpret_cast<float4*>(orow_) =                                      \
        make_float4(acc[T][0], acc[T][1], acc[T][2], acc[T][3]);             \
    *reinterpret_cast<float4*>(orow_ + 4) =                                  \
        make_float4(acc[T][4], acc[T][5], acc[T][6], acc[T][7]);             \
  }

__global__ __launch_bounds__(256) void dilate7(const float* __restrict__ x,
                                               const float* __restrict__ wg,
                                               float* __restrict__ out) {
  const int tid = threadIdx.x;
  const int lc = tid & 63;                       // 64 thread-cols per wave
  const int col0 = lc * 8;                       // output col base (mult of 8)
  // tid>>6 is the wave id -> row0 is wave-uniform; force it scalar.
  const int row0 =
      __builtin_amdgcn_readfirstlane(blockIdx.x * 32 + (tid >> 6) * 8);

  const size_t plane_off = (size_t)blockIdx.y * (size_t)(HH * WW);
  const float* xp = x + plane_off;
  float* op = out + plane_off;

  // Weights -> SGPRs (uniform loads).
  float wv[49];
#pragma unroll
  for (int i = 0; i < 49; ++i)
    wv[i] = __int_as_float(__builtin_amdgcn_readfirstlane(__float_as_int(wg[i])));

  const float* zrb = &ZROW[4];         // row base when the row is OOB
  const bool okL = (col0 >= 4);        // false only for lane with col0==0
  const bool okR = (col0 + 12 <= WW);  // false only for lane with col0==504

  float acc[8][8];                     // first write at K==t, no init needed
  float rv0[16], rv1[16], rv2[16];

  // 2-deep pipeline: load row K+2 while computing row K (buffer = K%3).
  LOADROW(rv0, 0);
  LOADROW(rv1, 1);
  LOADROW(rv2, 2);   COMPROW(rv0, 0);
  LOADROW(rv0, 3);   COMPROW(rv1, 1);
  LOADROW(rv1, 4);   COMPROW(rv2, 2);
  LOADROW(rv2, 5);   COMPROW(rv0, 3);
  LOADROW(rv0, 6);   COMPROW(rv1, 4);
  LOADROW(rv1, 7);   COMPROW(rv2, 5);
  LOADROW(rv2, 8);   COMPROW(rv0, 6);   STOREROW(0);
  LOADROW(rv0, 9);   COMPROW(rv1, 7);   STOREROW(1);
  LOADROW(rv1, 10);  COMPROW(rv2, 8);   STOREROW(2);
  LOADROW(rv2, 11);  COMPROW(rv0, 9);   STOREROW(3);
  LOADROW(rv0, 12);  COMPROW(rv1, 10);  STOREROW(4);
  LOADROW(rv1, 13);  COMPROW(rv2, 11);  STOREROW(5);
  COMPROW(rv0, 12);  STOREROW(6);
  COMPROW(rv1, 13);  STOREROW(7);
}

extern "C" void kernel_launch(void* const* d_in, const int* in_sizes, int n_in,
                              void* d_out, int out_size, void* d_ws, size_t ws_size,
                              hipStream_t stream) {
  const float* x = (const float*)d_in[0];
  const float* w = (const float*)d_in[1];
  float* out = (float*)d_out;
  const int planes = in_sizes[0] / (HH * WW);   // 8*8 = 64
  dim3 grid(16, planes);                        // 512x32 tile -> exact cover
  dilate7<<<grid, dim3(256, 1, 1), 0, stream>>>(x, w, out);
}

// Round 7
// 40.074 us; speedup vs baseline: 5.6641x; 1.3302x over previous
//
#include <hip/hip_runtime.h>

// Grayscale morphological dilation, 7x7 additive SE, zero 'same' padding:
//   out[p, i, j] = max_{a,b in 0..6} ( xz(p, i+a-3, j+b-3) + w[a,b] )
//
// R7: occupancy round. Thread tile 4 wide x 8 tall; block 256 = 64
// thread-cols x 4 waves -> block tile 256 cols x 32 rows; grid (2,16,64)
// = 2048 blocks = 8 blocks/CU = 8 waves/SIMD (was 4). Per-thread body
// halves (~16KB, fits I$). 1-deep prefetch (2 rotating literal-indexed
// buffers) -- TLP now hides memory latency instead of deep per-thread
// pipelining. Proven pieces kept: wave-uniform scalar row base with
// zero-row s_cselect for row OOB (saddr loads), per-lane zero-page
// cndmask only for the 2 edge chunks, SGPR weights via readfirstlane,
// early stores at K = t+6, literal indices everywhere (no scratch).

#define HH 512
#define WW 512

__device__ __align__(16) const float ZROW[16] = {};  // zero page

#define LOADROW(RV, K)                                                       \
  {                                                                          \
    const int r_ = row0 - 3 + (K);              /* scalar */                 \
    const float* rb_ = ((unsigned)r_ < (unsigned)HH)                         \
                           ? (xp + (ptrdiff_t)r_ * WW)                       \
                           : zrb;               /* s_cselect_b64 */          \
    const float* p0_ = okL ? rb_ + col0 - 4 : &ZROW[0];                      \
    const float* p2_ = okR ? rb_ + col0 + 4 : &ZROW[0];                      \
    float4 v0_ = *reinterpret_cast<const float4*>(p0_);                      \
    float4 v1_ = *reinterpret_cast<const float4*>(rb_ + col0);               \
    float4 v2_ = *reinterpret_cast<const float4*>(p2_);                      \
    RV[0] = v0_.x;  RV[1] = v0_.y;  RV[2] = v0_.z;  RV[3] = v0_.w;           \
    RV[4] = v1_.x;  RV[5] = v1_.y;  RV[6] = v1_.z;  RV[7] = v1_.w;           \
    RV[8] = v2_.x;  RV[9] = v2_.y;  RV[10] = v2_.z; RV[11] = v2_.w;          \
  }

// K is a literal at every expansion site; all indices fold at compile time.
#define COMPROW(RV, K)                                                       \
  {                                                                          \
    _Pragma("unroll") for (int t = 0; t < 8; ++t) {                          \
      if (t <= (K) && t + 6 >= (K)) { /* SE row a = K-t in 0..6 */           \
        const int a_ = (K) - t;                                              \
        _Pragma("unroll") for (int j = 0; j < 4; ++j) {                      \
          /* tap b: input col col0+j+b-3 -> RV[j+b+1] */                     \
          const float c0_ = RV[j + 1] + wv[a_ * 7 + 0];                      \
          const float c1_ = RV[j + 2] + wv[a_ * 7 + 1];                      \
          float m_ = ((K) == t) ? fmaxf(c0_, c1_)        /* first touch */   \
                                : fmaxf(acc[t][j], fmaxf(c0_, c1_));         \
          const float c2_ = RV[j + 3] + wv[a_ * 7 + 2];                      \
          const float c3_ = RV[j + 4] + wv[a_ * 7 + 3];                      \
          m_ = fmaxf(m_, fmaxf(c2_, c3_));               /* v_max3_f32 */    \
          const float c4_ = RV[j + 5] + wv[a_ * 7 + 4];                      \
          const float c5_ = RV[j + 6] + wv[a_ * 7 + 5];                      \
          m_ = fmaxf(m_, fmaxf(c4_, c5_));                                   \
          m_ = fmaxf(m_, RV[j + 7] + wv[a_ * 7 + 6]);                        \
          acc[t][j] = m_;                                                    \
        }                                                                    \
      }                                                                      \
    }                                                                        \
  }

#define STOREROW(T)                                                          \
  {                                                                          \
    float* orow_ = op + (ptrdiff_t)(row0 + (T)) * WW + col0;                 \
    *reinterpret_cast<float4*>(orow_) =                                      \
        make_float4(acc[T][0], acc[T][1], acc[T][2], acc[T][3]);             \
  }

__global__ __launch_bounds__(256) void dilate7(const float* __restrict__ x,
                                               const float* __restrict__ wg,
                                               float* __restrict__ out) {
  const int tid = threadIdx.x;
  const int lc = tid & 63;                          // 64 thread-cols per wave
  const int col0 = blockIdx.x * 256 + lc * 4;       // output col base (mult 4)
  // tid>>6 is the wave id -> row0 is wave-uniform; force it scalar.
  const int row0 =
      __builtin_amdgcn_readfirstlane(blockIdx.y * 32 + (tid >> 6) * 8);

  const size_t plane_off = (size_t)blockIdx.z * (size_t)(HH * WW);
  const float* xp = x + plane_off;
  float* op = out + plane_off;

  // Weights -> SGPRs (uniform loads).
  float wv[49];
#pragma unroll
  for (int i = 0; i < 49; ++i)
    wv[i] = __int_as_float(__builtin_amdgcn_readfirstlane(__float_as_int(wg[i])));

  const float* zrb = &ZROW[4];         // row base when the row is OOB
  const bool okL = (col0 >= 4);        // false only for global col0 == 0
  const bool okR = (col0 + 8 <= WW);   // false only for global col0 == 508

  float acc[8][4];                     // first write at K==t, no init needed
  float rvA[12], rvB[12];

  // 1-deep pipeline: load row K+1 while computing row K.
  LOADROW(rvA, 0);
  LOADROW(rvB, 1);   COMPROW(rvA, 0);
  LOADROW(rvA, 2);   COMPROW(rvB, 1);
  LOADROW(rvB, 3);   COMPROW(rvA, 2);
  LOADROW(rvA, 4);   COMPROW(rvB, 3);
  LOADROW(rvB, 5);   COMPROW(rvA, 4);
  LOADROW(rvA, 6);   COMPROW(rvB, 5);
  LOADROW(rvB, 7);   COMPROW(rvA, 6);   STOREROW(0);
  LOADROW(rvA, 8);   COMPROW(rvB, 7);   STOREROW(1);
  LOADROW(rvB, 9);   COMPROW(rvA, 8);   STOREROW(2);
  LOADROW(rvA, 10);  COMPROW(rvB, 9);   STOREROW(3);
  LOADROW(rvB, 11);  COMPROW(rvA, 10);  STOREROW(4);
  LOADROW(rvA, 12);  COMPROW(rvB, 11);  STOREROW(5);
  LOADROW(rvB, 13);  COMPROW(rvA, 12);  STOREROW(6);
  COMPROW(rvB, 13);  STOREROW(7);
}

extern "C" void kernel_launch(void* const* d_in, const int* in_sizes, int n_in,
                              void* d_out, int out_size, void* d_ws, size_t ws_size,
                              hipStream_t stream) {
  const float* x = (const float*)d_in[0];
  const float* w = (const float*)d_in[1];
  float* out = (float*)d_out;
  const int planes = in_sizes[0] / (HH * WW);   // 8*8 = 64
  dim3 grid(2, 16, planes);                     // 256x32 tile -> exact cover
  dilate7<<<grid, dim3(256, 1, 1), 0, stream>>>(x, w, out);
}

// Round 8
// 40.009 us; speedup vs baseline: 5.6733x; 1.0016x over previous
//
#include <hip/hip_runtime.h>

// Grayscale morphological dilation, 7x7 additive SE, zero 'same' padding:
//   out[p, i, j] = max_{a,b in 0..6} ( xz(p, i+a-3, j+b-3) + w[a,b] )
//
// R8: guaranteed v_max3_f32 via inline asm (T17) + op-minimal reduction
// tree: per output per SE-row: 7 adds + 3 max3 + 1 max (first touch: 3
// max3) = 76 ops/output vs ~73 theoretical floor (49 adds irreducible:
// every (input,weight) sum is distinct). Structure otherwise identical
// to R7 (40us): 4x8 thread tile, 256x32 block tile, grid (2,16,64) =
// 8 blocks/CU = max TLP; wave-uniform scalar row base with zero-row
// s_cselect; per-lane zero-page cndmask only for 2 edge chunks; SGPR
// weights via readfirstlane; 1-deep prefetch, literal indices only.

#define HH 512
#define WW 512

__device__ __align__(16) const float ZROW[16] = {};  // zero page

__device__ __forceinline__ float max3f(float a, float b, float c) {
  float d;
  asm("v_max3_f32 %0, %1, %2, %3" : "=v"(d) : "v"(a), "v"(b), "v"(c));
  return d;
}

#define LOADROW(RV, K)                                                       \
  {                                                                          \
    const int r_ = row0 - 3 + (K);              /* scalar */                 \
    const float* rb_ = ((unsigned)r_ < (unsigned)HH)                         \
                           ? (xp + (ptrdiff_t)r_ * WW)                       \
                           : zrb;               /* s_cselect_b64 */          \
    const float* p0_ = okL ? rb_ + col0 - 4 : &ZROW[0];                      \
    const float* p2_ = okR ? rb_ + col0 + 4 : &ZROW[0];                      \
    float4 v0_ = *reinterpret_cast<const float4*>(p0_);                      \
    float4 v1_ = *reinterpret_cast<const float4*>(rb_ + col0);               \
    float4 v2_ = *reinterpret_cast<const float4*>(p2_);                      \
    RV[0] = v0_.x;  RV[1] = v0_.y;  RV[2] = v0_.z;  RV[3] = v0_.w;           \
    RV[4] = v1_.x;  RV[5] = v1_.y;  RV[6] = v1_.z;  RV[7] = v1_.w;           \
    RV[8] = v2_.x;  RV[9] = v2_.y;  RV[10] = v2_.z; RV[11] = v2_.w;          \
  }

// K is a literal at every expansion site; all indices fold at compile time.
#define COMPROW(RV, K)                                                       \
  {                                                                          \
    _Pragma("unroll") for (int t = 0; t < 8; ++t) {                          \
      if (t <= (K) && t + 6 >= (K)) { /* SE row a = K-t in 0..6 */           \
        const int a_ = (K) - t;                                              \
        _Pragma("unroll") for (int j = 0; j < 4; ++j) {                      \
          /* tap b: input col col0+j+b-3 -> RV[j+b+1] */                     \
          const float c0_ = RV[j + 1] + wv[a_ * 7 + 0];                      \
          const float c1_ = RV[j + 2] + wv[a_ * 7 + 1];                      \
          const float c2_ = RV[j + 3] + wv[a_ * 7 + 2];                      \
          const float c3_ = RV[j + 4] + wv[a_ * 7 + 3];                      \
          const float c4_ = RV[j + 5] + wv[a_ * 7 + 4];                      \
          const float c5_ = RV[j + 6] + wv[a_ * 7 + 5];                      \
          const float c6_ = RV[j + 7] + wv[a_ * 7 + 6];                      \
          const float t1_ = max3f(c0_, c1_, c2_);                            \
          const float t2_ = max3f(c3_, c4_, c5_);                            \
          acc[t][j] = ((K) == t)                                             \
                          ? max3f(t1_, t2_, c6_)          /* first touch */  \
                          : max3f(t1_, t2_, fmaxf(c6_, acc[t][j]));          \
        }                                                                    \
      }                                                                      \
    }                                                                        \
  }

#define STOREROW(T)                                                          \
  {                                                                          \
    float* orow_ = op + (ptrdiff_t)(row0 + (T)) * WW + col0;                 \
    *reinterpret_cast<float4*>(orow_) =                                      \
        make_float4(acc[T][0], acc[T][1], acc[T][2], acc[T][3]);             \
  }

__global__ __launch_bounds__(256) void dilate7(const float* __restrict__ x,
                                               const float* __restrict__ wg,
                                               float* __restrict__ out) {
  const int tid = threadIdx.x;
  const int lc = tid & 63;                          // 64 thread-cols per wave
  const int col0 = blockIdx.x * 256 + lc * 4;       // output col base (mult 4)
  // tid>>6 is the wave id -> row0 is wave-uniform; force it scalar.
  const int row0 =
      __builtin_amdgcn_readfirstlane(blockIdx.y * 32 + (tid >> 6) * 8);

  const size_t plane_off = (size_t)blockIdx.z * (size_t)(HH * WW);
  const float* xp = x + plane_off;
  float* op = out + plane_off;

  // Weights -> SGPRs (uniform loads).
  float wv[49];
#pragma unroll
  for (int i = 0; i < 49; ++i)
    wv[i] = __int_as_float(__builtin_amdgcn_readfirstlane(__float_as_int(wg[i])));

  const float* zrb = &ZROW[4];         // row base when the row is OOB
  const bool okL = (col0 >= 4);        // false only for global col0 == 0
  const bool okR = (col0 + 8 <= WW);   // false only for global col0 == 508

  float acc[8][4];                     // first write at K==t, no init needed
  float rvA[12], rvB[12];

  // 1-deep pipeline: load row K+1 while computing row K.
  LOADROW(rvA, 0);
  LOADROW(rvB, 1);   COMPROW(rvA, 0);
  LOADROW(rvA, 2);   COMPROW(rvB, 1);
  LOADROW(rvB, 3);   COMPROW(rvA, 2);
  LOADROW(rvA, 4);   COMPROW(rvB, 3);
  LOADROW(rvB, 5);   COMPROW(rvA, 4);
  LOADROW(rvA, 6);   COMPROW(rvB, 5);
  LOADROW(rvB, 7);   COMPROW(rvA, 6);   STOREROW(0);
  LOADROW(rvA, 8);   COMPROW(rvB, 7);   STOREROW(1);
  LOADROW(rvB, 9);   COMPROW(rvA, 8);   STOREROW(2);
  LOADROW(rvA, 10);  COMPROW(rvB, 9);   STOREROW(3);
  LOADROW(rvB, 11);  COMPROW(rvA, 10);  STOREROW(4);
  LOADROW(rvA, 12);  COMPROW(rvB, 11);  STOREROW(5);
  LOADROW(rvB, 13);  COMPROW(rvA, 12);  STOREROW(6);
  COMPROW(rvB, 13);  STOREROW(7);
}

extern "C" void kernel_launch(void* const* d_in, const int* in_sizes, int n_in,
                              void* d_out, int out_size, void* d_ws, size_t ws_size,
                              hipStream_t stream) {
  const float* x = (const float*)d_in[0];
  const float* w = (const float*)d_in[1];
  float* out = (float*)d_out;
  const int planes = in_sizes[0] / (HH * WW);   // 8*8 = 64
  dim3 grid(2, 16, planes);                     // 256x32 tile -> exact cover
  dilate7<<<grid, dim3(256, 1, 1), 0, stream>>>(x, w, out);
}